// Round 1
// baseline (553.329 us; speedup 1.0000x reference)
//
#include <hip/hip_runtime.h>
#include <hip/hip_bf16.h>

// Problem constants (reference: N=8192 nodes, C=128 channels, E=262144 edges)
#define CCH 128

typedef __attribute__((ext_vector_type(8))) short s8v;   // 8 bf16 in 4 VGPRs (MFMA A/B frag)
typedef __attribute__((ext_vector_type(4))) float f4v;   // MFMA C/D frag

__device__ __forceinline__ unsigned short f2bf(float f){
  unsigned int u = __float_as_uint(f);
  u += 0x7fffu + ((u >> 16) & 1u);       // round-to-nearest-even
  return (unsigned short)(u >> 16);
}

// ---- degree histogram (in-degree over dst) ----
__global__ void k_deg(const int* __restrict__ dst, int* __restrict__ deg, int e){
  int i = blockIdx.x * blockDim.x + threadIdx.x;
  if (i < e) atomicAdd(&deg[dst[i]], 1);
}

// ---- dis = (deg+1)^-0.5 ----
__global__ void k_dis(const int* __restrict__ deg, float* __restrict__ dis, int n){
  int i = blockIdx.x * blockDim.x + threadIdx.x;
  if (i < n) dis[i] = rsqrtf((float)deg[i] + 1.0f);
}

// ---- exclusive scan of deg -> row_ptr (+ copy to cursor). n == 8192, 1 block x 1024 ----
__global__ void k_scan(const int* __restrict__ deg, int* __restrict__ row_ptr,
                       int* __restrict__ cursor, int n){
  __shared__ int part[1024];
  int t = threadIdx.x;
  int base = t * 8;
  int loc[8];
  int s = 0;
  #pragma unroll
  for (int i = 0; i < 8; ++i){ loc[i] = s; s += deg[base + i]; }
  part[t] = s;
  __syncthreads();
  for (int off = 1; off < 1024; off <<= 1){
    int v = (t >= off) ? part[t - off] : 0;
    __syncthreads();
    part[t] += v;
    __syncthreads();
  }
  int prev = t ? part[t - 1] : 0;
  #pragma unroll
  for (int i = 0; i < 8; ++i){
    int v = prev + loc[i];
    row_ptr[base + i] = v;
    cursor[base + i]  = v;
  }
  if (t == 0) row_ptr[n] = part[1023];
}

// ---- scatter edges into CSR by dst ----
__global__ void k_scatter(const int* __restrict__ src, const int* __restrict__ dst,
                          int* __restrict__ cursor, int* __restrict__ csr_src, int e){
  int i = blockIdx.x * blockDim.x + threadIdx.x;
  if (i < e){
    int d = dst[i];
    int pos = atomicAdd(&cursor[d], 1);
    csr_src[pos] = src[i];
  }
}

// ---- out[i] = dis[i] * sum_{e: dst=i} h[src_e]*dis[src_e]  +  h[i]*dis[i]^2 ----
// one wave per node, float2 per lane (64*2 = 128 channels)
__global__ __launch_bounds__(256) void k_agg(const float* __restrict__ h,
                                             const float* __restrict__ dis,
                                             const int* __restrict__ row_ptr,
                                             const int* __restrict__ csr_src,
                                             float* __restrict__ out, int n){
  int node = (blockIdx.x * blockDim.x + threadIdx.x) >> 6;
  int lane = threadIdx.x & 63;
  if (node >= n) return;
  const float2* h2 = (const float2*)h;
  int st = row_ptr[node], en = row_ptr[node + 1];
  float ax = 0.f, ay = 0.f;
  for (int e = st; e < en; ++e){
    int s = csr_src[e];
    float ds = dis[s];
    float2 v = h2[(size_t)s * 64 + lane];
    ax += v.x * ds; ay += v.y * ds;
  }
  float di = dis[node];
  float2 sv = h2[(size_t)node * 64 + lane];
  float2 o;
  o.x = ax * di + sv.x * di * di;
  o.y = ay * di + sv.y * di * di;
  ((float2*)out)[(size_t)node * 64 + lane] = o;
}

// ---- out = A @ W + b (optional relu). A: [n,128], W: [128,128]. 32 rows/block ----
__global__ __launch_bounds__(256) void k_gemm(const float* __restrict__ A,
                                              const float* __restrict__ W,
                                              const float* __restrict__ bias,
                                              float* __restrict__ out, int relu){
  __shared__ float sW[CCH * CCH];    // 64 KB
  __shared__ float sA[32 * CCH];     // 16 KB
  int tid = threadIdx.x;
  const float4* W4 = (const float4*)W;
  float4* sW4 = (float4*)sW;
  #pragma unroll
  for (int i = 0; i < 16; ++i) sW4[tid + i * 256] = W4[tid + i * 256];
  int row0 = blockIdx.x * 32;
  const float4* A4 = (const float4*)(A + (size_t)row0 * CCH);
  float4* sA4 = (float4*)sA;
  #pragma unroll
  for (int i = 0; i < 4; ++i) sA4[tid + i * 256] = A4[tid + i * 256];
  __syncthreads();

  int r  = (tid >> 4) << 1;     // 0,2,...,30
  int c0 = (tid & 15) << 3;     // 0,8,...,120
  float acc0[8] = {0}, acc1[8] = {0};
  for (int k = 0; k < CCH; ++k){
    float a0 = sA[r * CCH + k], a1 = sA[(r + 1) * CCH + k];
    const float* wr = &sW[k * CCH + c0];
    #pragma unroll
    for (int j = 0; j < 8; ++j){
      float w = wr[j];
      acc0[j] += a0 * w;
      acc1[j] += a1 * w;
    }
  }
  size_t g0 = (size_t)(row0 + r) * CCH + c0;
  #pragma unroll
  for (int j = 0; j < 8; ++j){
    float v0 = acc0[j] + bias[c0 + j];
    float v1 = acc1[j] + bias[c0 + j];
    if (relu){ v0 = fmaxf(v0, 0.f); v1 = fmaxf(v1, 0.f); }
    out[g0 + j] = v0;
    out[g0 + CCH + j] = v1;
  }
}

// ---- f32 -> bf16 conversion of s and t ----
__global__ void k_tobf16(const float4* __restrict__ a, const float4* __restrict__ b,
                         ushort4* __restrict__ ao, ushort4* __restrict__ bo, int total4){
  int i = blockIdx.x * blockDim.x + threadIdx.x;
  if (i < total4){
    float4 va = a[i];
    float4 vb = b[i];
    ushort4 oa = { f2bf(va.x), f2bf(va.y), f2bf(va.z), f2bf(va.w) };
    ushort4 ob = { f2bf(vb.x), f2bf(vb.y), f2bf(vb.z), f2bf(vb.w) };
    ao[i] = oa;
    bo[i] = ob;
  }
}

// ---- adj = S @ T^T, bf16 MFMA 16x16x32. 128x128 tile/block, 4 waves of 64x64 ----
__global__ __launch_bounds__(256) void k_adj(const unsigned short* __restrict__ S,
                                             const unsigned short* __restrict__ T,
                                             float* __restrict__ out, int n){
  __shared__ unsigned short sS[128 * 128];  // 32 KB, XOR-swizzled rows
  __shared__ unsigned short sT[128 * 128];  // 32 KB
  int tid = threadIdx.x;
  int ntile = n >> 7;                       // 64
  int tm = blockIdx.x / ntile;
  int tn = blockIdx.x % ntile;

  // stage both tiles: 2048 16B-chunks each, 8 per thread, coalesced in global
  #pragma unroll
  for (int i = 0; i < 8; ++i){
    int cidx = i * 256 + tid;
    int row = cidx >> 4;
    int o   = cidx & 15;
    int boff = (o * 16) ^ ((row & 7) << 4);     // bank-conflict swizzle (G4)
    s8v v = ((const s8v*)(S + (size_t)(tm * 128 + row) * CCH))[o];
    *(s8v*)((char*)sS + row * 256 + boff) = v;
    s8v w = ((const s8v*)(T + (size_t)(tn * 128 + row) * CCH))[o];
    *(s8v*)((char*)sT + row * 256 + boff) = w;
  }
  __syncthreads();

  int lane = tid & 63;
  int w = tid >> 6;
  int wm = (w >> 1) * 64;
  int wn = (w & 1) * 64;

  f4v zero = {0.f, 0.f, 0.f, 0.f};
  f4v acc[4][4];
  #pragma unroll
  for (int a = 0; a < 4; ++a)
    #pragma unroll
    for (int b = 0; b < 4; ++b) acc[a][b] = zero;

  #pragma unroll
  for (int ks = 0; ks < 4; ++ks){
    int boff = ks * 64 + (lane >> 4) * 16;
    s8v af[4], bf[4];
    #pragma unroll
    for (int mi = 0; mi < 4; ++mi){
      int row = wm + mi * 16 + (lane & 15);
      af[mi] = *(const s8v*)((const char*)sS + row * 256 + (boff ^ ((row & 7) << 4)));
    }
    #pragma unroll
    for (int ni = 0; ni < 4; ++ni){
      int row = wn + ni * 16 + (lane & 15);
      bf[ni] = *(const s8v*)((const char*)sT + row * 256 + (boff ^ ((row & 7) << 4)));
    }
    #pragma unroll
    for (int mi = 0; mi < 4; ++mi)
      #pragma unroll
      for (int ni = 0; ni < 4; ++ni)
        acc[mi][ni] = __builtin_amdgcn_mfma_f32_16x16x32_bf16(af[mi], bf[ni], acc[mi][ni], 0, 0, 0);
  }

  // C/D layout (m89-verified): col = lane&15, row = (lane>>4)*4 + reg
  int rbase = tm * 128 + wm + (lane >> 4) * 4;
  int cbase = tn * 128 + wn + (lane & 15);
  #pragma unroll
  for (int mi = 0; mi < 4; ++mi)
    #pragma unroll
    for (int ni = 0; ni < 4; ++ni){
      int rr = rbase + mi * 16;
      int cc = cbase + ni * 16;
      #pragma unroll
      for (int r = 0; r < 4; ++r)
        out[(size_t)(rr + r) * n + cc] = acc[mi][ni][r];
    }
}

extern "C" void kernel_launch(void* const* d_in, const int* in_sizes, int n_in,
                              void* d_out, int out_size, void* d_ws, size_t ws_size,
                              hipStream_t stream) {
  const float* x  = (const float*)d_in[0];
  const int*   ei = (const int*)d_in[1];
  const int n = in_sizes[0] / CCH;     // 8192
  const int e = in_sizes[1] / 2;       // 262144
  const int* srcv = ei;
  const int* dstv = ei + e;
  const float *Ws  = (const float*)d_in[2],  *bs  = (const float*)d_in[3];
  const float *Wt  = (const float*)d_in[4],  *bt  = (const float*)d_in[5];
  const float *W1  = (const float*)d_in[6],  *b1  = (const float*)d_in[7];
  const float *W2  = (const float*)d_in[8],  *b2  = (const float*)d_in[9];
  const float *Wmu = (const float*)d_in[10], *bmu = (const float*)d_in[11];
  const float *W5  = (const float*)d_in[12], *b5  = (const float*)d_in[13];
  const float *W6  = (const float*)d_in[14], *b6  = (const float*)d_in[15];

  char* ws = (char*)d_ws;
  size_t off = 0;
  auto alloc = [&](size_t bytes) -> void* {
    void* p = ws + off;
    off += (bytes + 255) & ~(size_t)255;
    return p;
  };
  int*   deg     = (int*)alloc((size_t)n * 4);
  float* dis     = (float*)alloc((size_t)n * 4);
  int*   row_ptr = (int*)alloc((size_t)(n + 1) * 4);
  int*   cursor  = (int*)alloc((size_t)n * 4);
  int*   csr_src = (int*)alloc((size_t)e * 4);
  float* aggX    = (float*)alloc((size_t)n * CCH * 4);
  float* sbuf    = (float*)alloc((size_t)n * CCH * 4);
  float* tbuf    = (float*)alloc((size_t)n * CCH * 4);
  float* P       = (float*)alloc((size_t)n * CCH * 4);
  float* Q       = (float*)alloc((size_t)n * CCH * 4);
  unsigned short* sb = (unsigned short*)alloc((size_t)n * CCH * 2);
  unsigned short* tb = (unsigned short*)alloc((size_t)n * CCH * 2);

  float* adj  = (float*)d_out;
  float* hout = (float*)d_out + (size_t)n * n;

  // graph preprocessing (recomputed every call; d_ws is re-poisoned)
  hipMemsetAsync(deg, 0, (size_t)n * 4, stream);
  k_deg    <<<(e + 255) / 256, 256, 0, stream>>>(dstv, deg, e);
  k_dis    <<<(n + 255) / 256, 256, 0, stream>>>(deg, dis, n);
  k_scan   <<<1, 1024, 0, stream>>>(deg, row_ptr, cursor, n);
  k_scatter<<<(e + 255) / 256, 256, 0, stream>>>(srcv, dstv, cursor, csr_src, e);

  // aggX = normAdj(x) used by s, t, and layer1
  k_agg <<<n / 4, 256, 0, stream>>>(x, dis, row_ptr, csr_src, aggX, n);
  k_gemm<<<n / 32, 256, 0, stream>>>(aggX, Ws, bs, sbuf, 0);
  k_gemm<<<n / 32, 256, 0, stream>>>(aggX, Wt, bt, tbuf, 0);
  k_gemm<<<n / 32, 256, 0, stream>>>(aggX, W1, b1, Q, 1);         // h1
  k_agg <<<n / 4, 256, 0, stream>>>(Q, dis, row_ptr, csr_src, P, n);
  k_gemm<<<n / 32, 256, 0, stream>>>(P, W2, b2, Q, 1);            // h2
  k_agg <<<n / 4, 256, 0, stream>>>(Q, dis, row_ptr, csr_src, P, n);
  k_gemm<<<n / 32, 256, 0, stream>>>(P, Wmu, bmu, Q, 0);          // hmu
  k_agg <<<n / 4, 256, 0, stream>>>(Q, dis, row_ptr, csr_src, P, n);
  k_gemm<<<n / 32, 256, 0, stream>>>(P, W5, b5, Q, 1);            // h5
  k_agg <<<n / 4, 256, 0, stream>>>(Q, dis, row_ptr, csr_src, P, n);
  k_gemm<<<n / 32, 256, 0, stream>>>(P, W6, b6, hout, 1);         // h6 -> output

  // adj_pred = s @ t^T in bf16 MFMA (single rounding, well under threshold)
  k_tobf16<<<((n * CCH / 4) + 255) / 256, 256, 0, stream>>>(
      (const float4*)sbuf, (const float4*)tbuf, (ushort4*)sb, (ushort4*)tb, n * CCH / 4);
  int nt = n / 128;
  k_adj<<<nt * nt, 256, 0, stream>>>(sb, tb, adj, n);
}

// Round 2
// 499.164 us; speedup vs baseline: 1.1085x; 1.1085x over previous
//
#include <hip/hip_runtime.h>
#include <hip/hip_bf16.h>

// N=8192 nodes, C=128 channels, E=262144 edges
#define CCH 128

typedef __attribute__((ext_vector_type(8))) short s8v;   // 8 bf16 (MFMA A/B frag)
typedef __attribute__((ext_vector_type(4))) float f4v;   // MFMA C/D frag

__device__ __forceinline__ unsigned short f2bf(float f){
  unsigned int u = __float_as_uint(f);
  u += 0x7fffu + ((u >> 16) & 1u);       // round-to-nearest-even
  return (unsigned short)(u >> 16);
}

// ---- degree histogram (in-degree over dst) ----
__global__ void k_deg(const int* __restrict__ dst, int* __restrict__ deg, int e){
  int i = blockIdx.x * blockDim.x + threadIdx.x;
  if (i < e) atomicAdd(&deg[dst[i]], 1);
}

// ---- dis = (deg+1)^-0.5 ; g0 = x * dis (row-scaled feature domain) ----
__global__ __launch_bounds__(256) void k_disscale(const int* __restrict__ deg,
    const float* __restrict__ x, float* __restrict__ dis, float* __restrict__ g, int n){
  int t = blockIdx.x * 256 + threadIdx.x;
  int i = t >> 5, c = t & 31;
  if (i >= n) return;
  float di = rsqrtf((float)deg[i] + 1.0f);
  if (c == 0) dis[i] = di;
  float4 v = ((const float4*)x)[(size_t)i * 32 + c];
  v.x *= di; v.y *= di; v.z *= di; v.w *= di;
  ((float4*)g)[(size_t)i * 32 + c] = v;
}

// ---- exclusive scan of deg -> row_ptr (+ cursor). n == 8192, 1 block x 1024 ----
__global__ void k_scan(const int* __restrict__ deg, int* __restrict__ row_ptr,
                       int* __restrict__ cursor, int n){
  __shared__ int part[1024];
  int t = threadIdx.x;
  int base = t * 8;
  int loc[8];
  int s = 0;
  #pragma unroll
  for (int i = 0; i < 8; ++i){ loc[i] = s; s += deg[base + i]; }
  part[t] = s;
  __syncthreads();
  for (int off = 1; off < 1024; off <<= 1){
    int v = (t >= off) ? part[t - off] : 0;
    __syncthreads();
    part[t] += v;
    __syncthreads();
  }
  int prev = t ? part[t - 1] : 0;
  #pragma unroll
  for (int i = 0; i < 8; ++i){
    int v = prev + loc[i];
    row_ptr[base + i] = v;
    cursor[base + i]  = v;
  }
  if (t == 0) row_ptr[n] = part[1023];
}

// ---- scatter edges into CSR by dst ----
__global__ void k_scatter(const int* __restrict__ src, const int* __restrict__ dst,
                          int* __restrict__ cursor, int* __restrict__ csr_src, int e){
  int i = blockIdx.x * blockDim.x + threadIdx.x;
  if (i < e){
    int d = dst[i];
    int pos = atomicAdd(&cursor[d], 1);
    csr_src[pos] = src[i];
  }
}

// ---- sum[i] = sum_{e: dst=i} g[src_e] + g[i]   (g is pre-scaled by dis) ----
// one wave per node, float2 per lane; edge loop unrolled x8 for MLP
__global__ __launch_bounds__(256) void k_agg(const float* __restrict__ g,
    const int* __restrict__ row_ptr, const int* __restrict__ csr_src,
    float* __restrict__ out, int n){
  int node = (blockIdx.x * blockDim.x + threadIdx.x) >> 6;
  int lane = threadIdx.x & 63;
  if (node >= n) return;
  node = __builtin_amdgcn_readfirstlane(node);   // force scalar row_ptr/csr loads
  const float2* g2 = (const float2*)g;
  int st = row_ptr[node], en = row_ptr[node + 1];
  float2 sv = g2[(size_t)node * 64 + lane];
  float ax0 = sv.x, ay0 = sv.y;        // self term folded into acc 0
  float ax1 = 0.f, ay1 = 0.f, ax2 = 0.f, ay2 = 0.f, ax3 = 0.f, ay3 = 0.f;
  float ax4 = 0.f, ay4 = 0.f, ax5 = 0.f, ay5 = 0.f, ax6 = 0.f, ay6 = 0.f;
  float ax7 = 0.f, ay7 = 0.f;
  int e = st;
  for (; e + 8 <= en; e += 8){
    int s0 = csr_src[e + 0], s1 = csr_src[e + 1], s2 = csr_src[e + 2], s3 = csr_src[e + 3];
    int s4 = csr_src[e + 4], s5 = csr_src[e + 5], s6 = csr_src[e + 6], s7 = csr_src[e + 7];
    float2 v0 = g2[(size_t)s0 * 64 + lane];
    float2 v1 = g2[(size_t)s1 * 64 + lane];
    float2 v2 = g2[(size_t)s2 * 64 + lane];
    float2 v3 = g2[(size_t)s3 * 64 + lane];
    float2 v4 = g2[(size_t)s4 * 64 + lane];
    float2 v5 = g2[(size_t)s5 * 64 + lane];
    float2 v6 = g2[(size_t)s6 * 64 + lane];
    float2 v7 = g2[(size_t)s7 * 64 + lane];
    ax0 += v0.x; ay0 += v0.y;  ax1 += v1.x; ay1 += v1.y;
    ax2 += v2.x; ay2 += v2.y;  ax3 += v3.x; ay3 += v3.y;
    ax4 += v4.x; ay4 += v4.y;  ax5 += v5.x; ay5 += v5.y;
    ax6 += v6.x; ay6 += v6.y;  ax7 += v7.x; ay7 += v7.y;
  }
  for (; e < en; ++e){
    int s = csr_src[e];
    float2 v = g2[(size_t)s * 64 + lane];
    ax0 += v.x; ay0 += v.y;
  }
  float2 o;
  o.x = ((ax0 + ax1) + (ax2 + ax3)) + ((ax4 + ax5) + (ax6 + ax7));
  o.y = ((ay0 + ay1) + (ay2 + ay3)) + ((ay4 + ay5) + (ay6 + ay7));
  ((float2*)out)[(size_t)node * 64 + lane] = o;
}

// ---- out = rowscale(dis)*(A @ W) + b, opt relu, opt out *= dis. 16 rows/block ----
__global__ __launch_bounds__(256) void k_gemm(const float* __restrict__ A,
    const float* __restrict__ W, const float* __restrict__ bias,
    const float* __restrict__ dis, float* __restrict__ out,
    int relu, int scale_out){
  __shared__ float sW[CCH * CCH];    // 64 KB
  __shared__ float sA[16 * CCH];     // 8 KB -> 72 KB total, 2 blocks/CU
  int tid = threadIdx.x;
  const float4* W4 = (const float4*)W;
  float4* sW4 = (float4*)sW;
  #pragma unroll
  for (int i = 0; i < 16; ++i) sW4[tid + i * 256] = W4[tid + i * 256];
  int row0 = blockIdx.x * 16;
  const float4* A4 = (const float4*)(A + (size_t)row0 * CCH);
  float4* sA4 = (float4*)sA;
  sA4[tid]       = A4[tid];
  sA4[tid + 256] = A4[tid + 256];
  __syncthreads();

  int r  = tid >> 4;            // 0..15 (one row per 16-thread group)
  int c0 = (tid & 15) << 3;     // 0,8,...,120
  float acc[8] = {0.f,0.f,0.f,0.f,0.f,0.f,0.f,0.f};
  #pragma unroll 4
  for (int k = 0; k < CCH; ++k){
    float a = sA[r * CCH + k];
    const float* wr = &sW[k * CCH + c0];
    #pragma unroll
    for (int j = 0; j < 8; ++j) acc[j] += a * wr[j];
  }
  float di = dis[row0 + r];
  size_t g0 = (size_t)(row0 + r) * CCH + c0;
  #pragma unroll
  for (int j = 0; j < 8; ++j){
    float v = fmaf(di, acc[j], bias[c0 + j]);   // (di*A)@W + b  == di*(A@W) + b
    if (relu) v = fmaxf(v, 0.f);
    if (scale_out) v *= di;                     // produce g = dis * h for next agg
    out[g0 + j] = v;
  }
}

// ---- f32 -> bf16 conversion of s and t ----
__global__ void k_tobf16(const float4* __restrict__ a, const float4* __restrict__ b,
                         ushort4* __restrict__ ao, ushort4* __restrict__ bo, int total4){
  int i = blockIdx.x * blockDim.x + threadIdx.x;
  if (i < total4){
    float4 va = a[i];
    float4 vb = b[i];
    ushort4 oa = { f2bf(va.x), f2bf(va.y), f2bf(va.z), f2bf(va.w) };
    ushort4 ob = { f2bf(vb.x), f2bf(vb.y), f2bf(vb.z), f2bf(vb.w) };
    ao[i] = oa;
    bo[i] = ob;
  }
}

// ---- adj = S @ T^T, bf16 MFMA 16x16x32. 128x128 tile/block, 4 waves of 64x64 ----
__global__ __launch_bounds__(256) void k_adj(const unsigned short* __restrict__ S,
                                             const unsigned short* __restrict__ T,
                                             float* __restrict__ out, int n){
  __shared__ unsigned short sS[128 * 128];  // 32 KB, XOR-swizzled rows
  __shared__ unsigned short sT[128 * 128];  // 32 KB
  int tid = threadIdx.x;
  int ntile = n >> 7;                       // 64
  int tm = blockIdx.x / ntile;
  int tn = blockIdx.x % ntile;

  #pragma unroll
  for (int i = 0; i < 8; ++i){
    int cidx = i * 256 + tid;
    int row = cidx >> 4;
    int o   = cidx & 15;
    int boff = (o * 16) ^ ((row & 7) << 4);     // bank-conflict swizzle (G4)
    s8v v = ((const s8v*)(S + (size_t)(tm * 128 + row) * CCH))[o];
    *(s8v*)((char*)sS + row * 256 + boff) = v;
    s8v w = ((const s8v*)(T + (size_t)(tn * 128 + row) * CCH))[o];
    *(s8v*)((char*)sT + row * 256 + boff) = w;
  }
  __syncthreads();

  int lane = tid & 63;
  int w = tid >> 6;
  int wm = (w >> 1) * 64;
  int wn = (w & 1) * 64;

  f4v zero = {0.f, 0.f, 0.f, 0.f};
  f4v acc[4][4];
  #pragma unroll
  for (int a = 0; a < 4; ++a)
    #pragma unroll
    for (int b = 0; b < 4; ++b) acc[a][b] = zero;

  #pragma unroll
  for (int ks = 0; ks < 4; ++ks){
    int boff = ks * 64 + (lane >> 4) * 16;
    s8v af[4], bf[4];
    #pragma unroll
    for (int mi = 0; mi < 4; ++mi){
      int row = wm + mi * 16 + (lane & 15);
      af[mi] = *(const s8v*)((const char*)sS + row * 256 + (boff ^ ((row & 7) << 4)));
    }
    #pragma unroll
    for (int ni = 0; ni < 4; ++ni){
      int row = wn + ni * 16 + (lane & 15);
      bf[ni] = *(const s8v*)((const char*)sT + row * 256 + (boff ^ ((row & 7) << 4)));
    }
    #pragma unroll
    for (int mi = 0; mi < 4; ++mi)
      #pragma unroll
      for (int ni = 0; ni < 4; ++ni)
        acc[mi][ni] = __builtin_amdgcn_mfma_f32_16x16x32_bf16(af[mi], bf[ni], acc[mi][ni], 0, 0, 0);
  }

  // C/D layout (m89-verified): col = lane&15, row = (lane>>4)*4 + reg
  int rbase = tm * 128 + wm + (lane >> 4) * 4;
  int cbase = tn * 128 + wn + (lane & 15);
  #pragma unroll
  for (int mi = 0; mi < 4; ++mi)
    #pragma unroll
    for (int ni = 0; ni < 4; ++ni){
      int rr = rbase + mi * 16;
      int cc = cbase + ni * 16;
      #pragma unroll
      for (int r = 0; r < 4; ++r)
        out[(size_t)(rr + r) * n + cc] = acc[mi][ni][r];
    }
}

extern "C" void kernel_launch(void* const* d_in, const int* in_sizes, int n_in,
                              void* d_out, int out_size, void* d_ws, size_t ws_size,
                              hipStream_t stream) {
  const float* x  = (const float*)d_in[0];
  const int*   ei = (const int*)d_in[1];
  const int n = in_sizes[0] / CCH;     // 8192
  const int e = in_sizes[1] / 2;       // 262144
  const int* srcv = ei;
  const int* dstv = ei + e;
  const float *Ws  = (const float*)d_in[2],  *bs  = (const float*)d_in[3];
  const float *Wt  = (const float*)d_in[4],  *bt  = (const float*)d_in[5];
  const float *W1  = (const float*)d_in[6],  *b1  = (const float*)d_in[7];
  const float *W2  = (const float*)d_in[8],  *b2  = (const float*)d_in[9];
  const float *Wmu = (const float*)d_in[10], *bmu = (const float*)d_in[11];
  const float *W5  = (const float*)d_in[12], *b5  = (const float*)d_in[13];
  const float *W6  = (const float*)d_in[14], *b6  = (const float*)d_in[15];

  char* ws = (char*)d_ws;
  size_t off = 0;
  auto alloc = [&](size_t bytes) -> void* {
    void* p = ws + off;
    off += (bytes + 255) & ~(size_t)255;
    return p;
  };
  int*   deg     = (int*)alloc((size_t)n * 4);
  float* dis     = (float*)alloc((size_t)n * 4);
  int*   row_ptr = (int*)alloc((size_t)(n + 1) * 4);
  int*   cursor  = (int*)alloc((size_t)n * 4);
  int*   csr_src = (int*)alloc((size_t)e * 4);
  float* g0      = (float*)alloc((size_t)n * CCH * 4);
  float* sumX    = (float*)alloc((size_t)n * CCH * 4);
  float* sbuf    = (float*)alloc((size_t)n * CCH * 4);
  float* tbuf    = (float*)alloc((size_t)n * CCH * 4);
  float* bufA    = (float*)alloc((size_t)n * CCH * 4);
  float* bufB    = (float*)alloc((size_t)n * CCH * 4);
  unsigned short* sb = (unsigned short*)alloc((size_t)n * CCH * 2);
  unsigned short* tb = (unsigned short*)alloc((size_t)n * CCH * 2);

  float* adj  = (float*)d_out;
  float* hout = (float*)d_out + (size_t)n * n;

  // graph preprocessing (recomputed every call)
  hipMemsetAsync(deg, 0, (size_t)n * 4, stream);
  k_deg     <<<(e + 255) / 256, 256, 0, stream>>>(dstv, deg, e);
  k_scan    <<<1, 1024, 0, stream>>>(deg, row_ptr, cursor, n);
  k_disscale<<<(n * 32) / 256, 256, 0, stream>>>(deg, x, dis, g0, n);
  k_scatter <<<(e + 255) / 256, 256, 0, stream>>>(srcv, dstv, cursor, csr_src, e);

  // layer 0: sumX reused by s, t, h1
  k_agg <<<n / 4, 256, 0, stream>>>(g0, row_ptr, csr_src, sumX, n);
  k_gemm<<<n / 16, 256, 0, stream>>>(sumX, Ws, bs, dis, sbuf, 0, 0);   // s (unscaled)
  k_gemm<<<n / 16, 256, 0, stream>>>(sumX, Wt, bt, dis, tbuf, 0, 0);   // t (unscaled)
  k_gemm<<<n / 16, 256, 0, stream>>>(sumX, W1, b1, dis, bufA, 1, 1);   // g1 = dis*relu(h1)

  // adj = s @ t^T (bf16 MFMA)
  k_tobf16<<<((n * CCH / 4) + 255) / 256, 256, 0, stream>>>(
      (const float4*)sbuf, (const float4*)tbuf, (ushort4*)sb, (ushort4*)tb, n * CCH / 4);
  int nt = n / 128;
  k_adj<<<nt * nt, 256, 0, stream>>>(sb, tb, adj, n);

  // remaining NodeModel layers (all in g = dis*h domain)
  k_agg <<<n / 4, 256, 0, stream>>>(bufA, row_ptr, csr_src, sumX, n);
  k_gemm<<<n / 16, 256, 0, stream>>>(sumX, W2, b2, dis, bufB, 1, 1);   // g2
  k_agg <<<n / 4, 256, 0, stream>>>(bufB, row_ptr, csr_src, sumX, n);
  k_gemm<<<n / 16, 256, 0, stream>>>(sumX, Wmu, bmu, dis, bufA, 0, 1); // gmu (no relu)
  k_agg <<<n / 4, 256, 0, stream>>>(bufA, row_ptr, csr_src, sumX, n);
  k_gemm<<<n / 16, 256, 0, stream>>>(sumX, W5, b5, dis, bufB, 1, 1);   // g5
  k_agg <<<n / 4, 256, 0, stream>>>(bufB, row_ptr, csr_src, sumX, n);
  k_gemm<<<n / 16, 256, 0, stream>>>(sumX, W6, b6, dis, hout, 1, 0);   // h6 (unscaled)
}

// Round 3
// 462.245 us; speedup vs baseline: 1.1970x; 1.0799x over previous
//
#include <hip/hip_runtime.h>
#include <hip/hip_bf16.h>

// N=8192 nodes, C=128 channels, E=262144 edges
#define CCH 128
#define NADJ 4096   // adj tile blocks (64x64 tiles of 128x128)

typedef __attribute__((ext_vector_type(8))) short s8v;   // 8 bf16 (MFMA A/B frag)
typedef __attribute__((ext_vector_type(4))) float f4v;   // MFMA C/D frag

__device__ __forceinline__ unsigned short f2bf(float f){
  unsigned int u = __float_as_uint(f);
  u += 0x7fffu + ((u >> 16) & 1u);       // round-to-nearest-even
  return (unsigned short)(u >> 16);
}
__device__ __forceinline__ float bf2f(unsigned short h){
  return __uint_as_float(((unsigned int)h) << 16);
}

// ---- degree histogram (in-degree over dst) ----
__global__ void k_deg(const int* __restrict__ dst, int* __restrict__ deg, int e){
  int i = blockIdx.x * blockDim.x + threadIdx.x;
  if (i < e) atomicAdd(&deg[dst[i]], 1);
}

// ---- dis = (deg+1)^-0.5 ; g0 = x * dis ----
__global__ __launch_bounds__(256) void k_disscale(const int* __restrict__ deg,
    const float* __restrict__ x, float* __restrict__ dis, float* __restrict__ g, int n){
  int t = blockIdx.x * 256 + threadIdx.x;
  int i = t >> 5, c = t & 31;
  if (i >= n) return;
  float di = rsqrtf((float)deg[i] + 1.0f);
  if (c == 0) dis[i] = di;
  float4 v = ((const float4*)x)[(size_t)i * 32 + c];
  v.x *= di; v.y *= di; v.z *= di; v.w *= di;
  ((float4*)g)[(size_t)i * 32 + c] = v;
}

// ---- exclusive scan of deg -> row_ptr (+ cursor). n == 8192, 1 block x 1024 ----
__global__ void k_scan(const int* __restrict__ deg, int* __restrict__ row_ptr,
                       int* __restrict__ cursor, int n){
  __shared__ int part[1024];
  int t = threadIdx.x;
  int base = t * 8;
  int loc[8];
  int s = 0;
  #pragma unroll
  for (int i = 0; i < 8; ++i){ loc[i] = s; s += deg[base + i]; }
  part[t] = s;
  __syncthreads();
  for (int off = 1; off < 1024; off <<= 1){
    int v = (t >= off) ? part[t - off] : 0;
    __syncthreads();
    part[t] += v;
    __syncthreads();
  }
  int prev = t ? part[t - 1] : 0;
  #pragma unroll
  for (int i = 0; i < 8; ++i){
    int v = prev + loc[i];
    row_ptr[base + i] = v;
    cursor[base + i]  = v;
  }
  if (t == 0) row_ptr[n] = part[1023];
}

// ---- scatter edges into CSR by dst ----
__global__ void k_scatter(const int* __restrict__ src, const int* __restrict__ dst,
                          int* __restrict__ cursor, int* __restrict__ csr_src, int e){
  int i = blockIdx.x * blockDim.x + threadIdx.x;
  if (i < e){
    int d = dst[i];
    int pos = atomicAdd(&cursor[d], 1);
    csr_src[pos] = src[i];
  }
}

// ---- split 7 weight matrices into transposed bf16 hi/lo: Wt[l][n][k] ----
__global__ __launch_bounds__(256) void k_wsplit(
    const float* __restrict__ w0, const float* __restrict__ w1, const float* __restrict__ w2,
    const float* __restrict__ w3, const float* __restrict__ w4, const float* __restrict__ w5,
    const float* __restrict__ w6,
    unsigned short* __restrict__ Wth, unsigned short* __restrict__ Wtl){
  int l = blockIdx.x >> 2;
  int seg = blockIdx.x & 3;
  const float* W;
  switch (l){
    case 0: W = w0; break; case 1: W = w1; break; case 2: W = w2; break;
    case 3: W = w3; break; case 4: W = w4; break; case 5: W = w5; break;
    default: W = w6; break;
  }
  unsigned short* oh = Wth + (size_t)l * 16384;
  unsigned short* ol = Wtl + (size_t)l * 16384;
  #pragma unroll
  for (int j = 0; j < 16; ++j){
    int i = seg * 4096 + j * 256 + threadIdx.x;
    int nn = i >> 7, kk = i & 127;
    float v = W[kk * CCH + nn];
    unsigned short h = f2bf(v);
    unsigned short lo = f2bf(v - bf2f(h));
    oh[i] = h;
    ol[i] = lo;
  }
}

// ---- aggregate one node (sum of g over in-edges + self), emit bf16 hi/lo ----
__device__ __forceinline__ void agg_body(int node, int lane, const float* __restrict__ g,
    const int* __restrict__ row_ptr, const int* __restrict__ csr_src,
    unsigned short* __restrict__ Ahi, unsigned short* __restrict__ Alo){
  const float2* g2 = (const float2*)g;
  int st = row_ptr[node], en = row_ptr[node + 1];
  float2 sv = g2[(size_t)node * 64 + lane];
  float ax0 = sv.x, ay0 = sv.y;
  float ax1 = 0.f, ay1 = 0.f, ax2 = 0.f, ay2 = 0.f, ax3 = 0.f, ay3 = 0.f;
  float ax4 = 0.f, ay4 = 0.f, ax5 = 0.f, ay5 = 0.f, ax6 = 0.f, ay6 = 0.f;
  float ax7 = 0.f, ay7 = 0.f;
  int e = st;
  for (; e + 8 <= en; e += 8){
    int s0 = csr_src[e + 0], s1 = csr_src[e + 1], s2 = csr_src[e + 2], s3 = csr_src[e + 3];
    int s4 = csr_src[e + 4], s5 = csr_src[e + 5], s6 = csr_src[e + 6], s7 = csr_src[e + 7];
    float2 v0 = g2[(size_t)s0 * 64 + lane];
    float2 v1 = g2[(size_t)s1 * 64 + lane];
    float2 v2 = g2[(size_t)s2 * 64 + lane];
    float2 v3 = g2[(size_t)s3 * 64 + lane];
    float2 v4 = g2[(size_t)s4 * 64 + lane];
    float2 v5 = g2[(size_t)s5 * 64 + lane];
    float2 v6 = g2[(size_t)s6 * 64 + lane];
    float2 v7 = g2[(size_t)s7 * 64 + lane];
    ax0 += v0.x; ay0 += v0.y;  ax1 += v1.x; ay1 += v1.y;
    ax2 += v2.x; ay2 += v2.y;  ax3 += v3.x; ay3 += v3.y;
    ax4 += v4.x; ay4 += v4.y;  ax5 += v5.x; ay5 += v5.y;
    ax6 += v6.x; ay6 += v6.y;  ax7 += v7.x; ay7 += v7.y;
  }
  for (; e < en; ++e){
    int s = csr_src[e];
    float2 v = g2[(size_t)s * 64 + lane];
    ax0 += v.x; ay0 += v.y;
  }
  float ox = ((ax0 + ax1) + (ax2 + ax3)) + ((ax4 + ax5) + (ax6 + ax7));
  float oy = ((ay0 + ay1) + (ay2 + ay3)) + ((ay4 + ay5) + (ay6 + ay7));
  unsigned short hx = f2bf(ox);
  unsigned short lx = f2bf(ox - bf2f(hx));
  unsigned short hy = f2bf(oy);
  unsigned short ly = f2bf(oy - bf2f(hy));
  ushort2 hv, lv;
  hv.x = hx; hv.y = hy;
  lv.x = lx; lv.y = ly;
  ((ushort2*)Ahi)[(size_t)node * 64 + lane] = hv;
  ((ushort2*)Alo)[(size_t)node * 64 + lane] = lv;
}

__global__ __launch_bounds__(256) void k_agg(const float* __restrict__ g,
    const int* __restrict__ row_ptr, const int* __restrict__ csr_src,
    unsigned short* __restrict__ Ahi, unsigned short* __restrict__ Alo, int n){
  int node = (blockIdx.x * blockDim.x + threadIdx.x) >> 6;
  int lane = threadIdx.x & 63;
  if (node >= n) return;
  node = __builtin_amdgcn_readfirstlane(node);
  agg_body(node, lane, g, row_ptr, csr_src, Ahi, Alo);
}

// ---- MFMA GEMM: out_l = epilogue( dis*(A@W_l) + b_l ) for up to 3 weights ----
// A in bf16 hi/lo (bf16x3: hihi + hilo + lohi ~ f32 accuracy). 32 rows/block.
// mode bits: 1=relu, 2=post-scale by dis (emit g), 4=bf16 output
struct GemmArgs {
  const unsigned short* wh[3];
  const unsigned short* wl[3];
  const float* bias[3];
  void* out[3];
  int mode[3];
  int nw;
};

__global__ __launch_bounds__(256) void k_gemm(const unsigned short* __restrict__ Ahi,
    const unsigned short* __restrict__ Alo, const float* __restrict__ dis, GemmArgs args){
  __shared__ unsigned short sAh[32 * CCH];   // 8 KB, swizzled
  __shared__ unsigned short sAl[32 * CCH];   // 8 KB
  __shared__ unsigned short sWh[CCH * CCH];  // 32 KB (transposed: rows are n)
  __shared__ unsigned short sWl[CCH * CCH];  // 32 KB  -> 80 KB total, 2 blocks/CU
  int tid = threadIdx.x;
  int row0 = blockIdx.x * 32;

  // stage A hi/lo (2 chunks of 16B per thread per array)
  #pragma unroll
  for (int j = 0; j < 2; ++j){
    int c = j * 256 + tid;
    int row = c >> 4, o = c & 15;
    int boff = (o * 16) ^ ((row & 7) << 4);
    *(s8v*)((char*)sAh + row * 256 + boff) = ((const s8v*)(Ahi + (size_t)(row0 + row) * CCH))[o];
    *(s8v*)((char*)sAl + row * 256 + boff) = ((const s8v*)(Alo + (size_t)(row0 + row) * CCH))[o];
  }
  // stage W[0]
  {
    const unsigned short* wh = args.wh[0];
    const unsigned short* wl = args.wl[0];
    #pragma unroll
    for (int j = 0; j < 8; ++j){
      int c = j * 256 + tid;
      int row = c >> 4, o = c & 15;
      int boff = (o * 16) ^ ((row & 7) << 4);
      *(s8v*)((char*)sWh + row * 256 + boff) = ((const s8v*)(wh + (size_t)row * CCH))[o];
      *(s8v*)((char*)sWl + row * 256 + boff) = ((const s8v*)(wl + (size_t)row * CCH))[o];
    }
  }
  __syncthreads();

  int lane = tid & 63;
  int w = tid >> 6;                 // wave -> 32-col slice

  // A fragments once (LDS A region is never overwritten)
  s8v ah[2][4], al[2][4];
  #pragma unroll
  for (int mi = 0; mi < 2; ++mi){
    int row = mi * 16 + (lane & 15);
    int sw = (row & 7) << 4;
    #pragma unroll
    for (int ks = 0; ks < 4; ++ks){
      int boff = (ks * 64 + ((lane >> 4) * 16)) ^ sw;
      ah[mi][ks] = *(const s8v*)((const char*)sAh + row * 256 + boff);
      al[mi][ks] = *(const s8v*)((const char*)sAl + row * 256 + boff);
    }
  }

  for (int l = 0; ; ++l){
    f4v zero = {0.f, 0.f, 0.f, 0.f};
    f4v acc[2][2];
    acc[0][0] = zero; acc[0][1] = zero; acc[1][0] = zero; acc[1][1] = zero;

    #pragma unroll
    for (int ks = 0; ks < 4; ++ks){
      s8v bh[2], bl[2];
      #pragma unroll
      for (int ni = 0; ni < 2; ++ni){
        int row = w * 32 + ni * 16 + (lane & 15);
        int boff = (ks * 64 + ((lane >> 4) * 16)) ^ ((row & 7) << 4);
        bh[ni] = *(const s8v*)((const char*)sWh + row * 256 + boff);
        bl[ni] = *(const s8v*)((const char*)sWl + row * 256 + boff);
      }
      #pragma unroll
      for (int mi = 0; mi < 2; ++mi)
        #pragma unroll
        for (int ni = 0; ni < 2; ++ni){
          acc[mi][ni] = __builtin_amdgcn_mfma_f32_16x16x32_bf16(ah[mi][ks], bh[ni], acc[mi][ni], 0, 0, 0);
          acc[mi][ni] = __builtin_amdgcn_mfma_f32_16x16x32_bf16(ah[mi][ks], bl[ni], acc[mi][ni], 0, 0, 0);
          acc[mi][ni] = __builtin_amdgcn_mfma_f32_16x16x32_bf16(al[mi][ks], bh[ni], acc[mi][ni], 0, 0, 0);
        }
    }

    // epilogue: C/D layout col = lane&15, row = (lane>>4)*4 + reg
    int mode = args.mode[l];
    const float* bp = args.bias[l];
    #pragma unroll
    for (int mi = 0; mi < 2; ++mi){
      f4v dv = ((const f4v*)(dis + row0 + mi * 16))[lane >> 4];   // 4 consecutive rows
      #pragma unroll
      for (int ni = 0; ni < 2; ++ni){
        int ccol = w * 32 + ni * 16 + (lane & 15);
        float bv = bp[ccol];
        #pragma unroll
        for (int rr = 0; rr < 4; ++rr){
          int rloc = mi * 16 + (lane >> 4) * 4 + rr;
          float di = dv[rr];
          float v = fmaf(di, acc[mi][ni][rr], bv);
          if (mode & 1) v = fmaxf(v, 0.f);
          if (mode & 2) v *= di;
          size_t gidx = (size_t)(row0 + rloc) * CCH + ccol;
          if (mode & 4) ((unsigned short*)args.out[l])[gidx] = f2bf(v);
          else          ((float*)args.out[l])[gidx] = v;
        }
      }
    }
    if (l + 1 >= args.nw) break;
    __syncthreads();
    {
      const unsigned short* wh = args.wh[l + 1];
      const unsigned short* wl = args.wl[l + 1];
      #pragma unroll
      for (int j = 0; j < 8; ++j){
        int c = j * 256 + tid;
        int row = c >> 4, o = c & 15;
        int boff = (o * 16) ^ ((row & 7) << 4);
        *(s8v*)((char*)sWh + row * 256 + boff) = ((const s8v*)(wh + (size_t)row * CCH))[o];
        *(s8v*)((char*)sWl + row * 256 + boff) = ((const s8v*)(wl + (size_t)row * CCH))[o];
      }
    }
    __syncthreads();
  }
}

// ---- merged: blocks [0,4096) adj = S@T^T; blocks [4096,6144) agg layer-2 ----
__global__ __launch_bounds__(256) void k_adjagg(const unsigned short* __restrict__ S,
    const unsigned short* __restrict__ T, float* __restrict__ out, int n,
    const float* __restrict__ g, const int* __restrict__ row_ptr,
    const int* __restrict__ csr_src, unsigned short* __restrict__ Ahi,
    unsigned short* __restrict__ Alo){
  if (blockIdx.x >= NADJ){
    int node = ((blockIdx.x - NADJ) * 256 + threadIdx.x) >> 6;
    int lane = threadIdx.x & 63;
    if (node >= n) return;
    node = __builtin_amdgcn_readfirstlane(node);
    agg_body(node, lane, g, row_ptr, csr_src, Ahi, Alo);
    return;
  }
  __shared__ unsigned short sS[128 * 128];  // 32 KB, XOR-swizzled rows
  __shared__ unsigned short sT[128 * 128];  // 32 KB
  int tid = threadIdx.x;
  int ntile = n >> 7;                       // 64
  int tm = blockIdx.x / ntile;
  int tn = blockIdx.x % ntile;

  #pragma unroll
  for (int i = 0; i < 8; ++i){
    int cidx = i * 256 + tid;
    int row = cidx >> 4;
    int o   = cidx & 15;
    int boff = (o * 16) ^ ((row & 7) << 4);
    s8v v = ((const s8v*)(S + (size_t)(tm * 128 + row) * CCH))[o];
    *(s8v*)((char*)sS + row * 256 + boff) = v;
    s8v w2 = ((const s8v*)(T + (size_t)(tn * 128 + row) * CCH))[o];
    *(s8v*)((char*)sT + row * 256 + boff) = w2;
  }
  __syncthreads();

  int lane = tid & 63;
  int w = tid >> 6;
  int wm = (w >> 1) * 64;
  int wn = (w & 1) * 64;

  f4v zero = {0.f, 0.f, 0.f, 0.f};
  f4v acc[4][4];
  #pragma unroll
  for (int a = 0; a < 4; ++a)
    #pragma unroll
    for (int b = 0; b < 4; ++b) acc[a][b] = zero;

  #pragma unroll
  for (int ks = 0; ks < 4; ++ks){
    int boff = ks * 64 + (lane >> 4) * 16;
    s8v af[4], bf[4];
    #pragma unroll
    for (int mi = 0; mi < 4; ++mi){
      int row = wm + mi * 16 + (lane & 15);
      af[mi] = *(const s8v*)((const char*)sS + row * 256 + (boff ^ ((row & 7) << 4)));
    }
    #pragma unroll
    for (int ni = 0; ni < 4; ++ni){
      int row = wn + ni * 16 + (lane & 15);
      bf[ni] = *(const s8v*)((const char*)sT + row * 256 + (boff ^ ((row & 7) << 4)));
    }
    #pragma unroll
    for (int mi = 0; mi < 4; ++mi)
      #pragma unroll
      for (int ni = 0; ni < 4; ++ni)
        acc[mi][ni] = __builtin_amdgcn_mfma_f32_16x16x32_bf16(af[mi], bf[ni], acc[mi][ni], 0, 0, 0);
  }

  int rbase = tm * 128 + wm + (lane >> 4) * 4;
  int cbase = tn * 128 + wn + (lane & 15);
  #pragma unroll
  for (int mi = 0; mi < 4; ++mi)
    #pragma unroll
    for (int ni = 0; ni < 4; ++ni){
      int rr = rbase + mi * 16;
      int cc = cbase + ni * 16;
      #pragma unroll
      for (int r = 0; r < 4; ++r)
        out[(size_t)(rr + r) * n + cc] = acc[mi][ni][r];
    }
}

extern "C" void kernel_launch(void* const* d_in, const int* in_sizes, int n_in,
                              void* d_out, int out_size, void* d_ws, size_t ws_size,
                              hipStream_t stream) {
  const float* x  = (const float*)d_in[0];
  const int*   ei = (const int*)d_in[1];
  const int n = in_sizes[0] / CCH;     // 8192
  const int e = in_sizes[1] / 2;       // 262144
  const int* srcv = ei;
  const int* dstv = ei + e;
  const float *Ws  = (const float*)d_in[2],  *bs  = (const float*)d_in[3];
  const float *Wt  = (const float*)d_in[4],  *bt  = (const float*)d_in[5];
  const float *W1  = (const float*)d_in[6],  *b1  = (const float*)d_in[7];
  const float *W2  = (const float*)d_in[8],  *b2  = (const float*)d_in[9];
  const float *Wmu = (const float*)d_in[10], *bmu = (const float*)d_in[11];
  const float *W5  = (const float*)d_in[12], *b5  = (const float*)d_in[13];
  const float *W6  = (const float*)d_in[14], *b6  = (const float*)d_in[15];

  char* ws = (char*)d_ws;
  size_t off = 0;
  auto alloc = [&](size_t bytes) -> void* {
    void* p = ws + off;
    off += (bytes + 255) & ~(size_t)255;
    return p;
  };
  int*   deg     = (int*)alloc((size_t)n * 4);
  float* dis     = (float*)alloc((size_t)n * 4);
  int*   row_ptr = (int*)alloc((size_t)(n + 1) * 4);
  int*   cursor  = (int*)alloc((size_t)n * 4);
  int*   csr_src = (int*)alloc((size_t)e * 4);
  float* gbuf    = (float*)alloc((size_t)n * CCH * 4);           // g (f32), reused each layer
  unsigned short* Ahi = (unsigned short*)alloc((size_t)n * CCH * 2);
  unsigned short* Alo = (unsigned short*)alloc((size_t)n * CCH * 2);
  unsigned short* sb  = (unsigned short*)alloc((size_t)n * CCH * 2);
  unsigned short* tb  = (unsigned short*)alloc((size_t)n * CCH * 2);
  unsigned short* Wth = (unsigned short*)alloc((size_t)7 * 16384 * 2);
  unsigned short* Wtl = (unsigned short*)alloc((size_t)7 * 16384 * 2);

  float* adj  = (float*)d_out;
  float* hout = (float*)d_out + (size_t)n * n;

  // graph preprocessing
  hipMemsetAsync(deg, 0, (size_t)n * 4, stream);
  k_deg     <<<(e + 255) / 256, 256, 0, stream>>>(dstv, deg, e);
  k_scan    <<<1, 1024, 0, stream>>>(deg, row_ptr, cursor, n);
  k_disscale<<<(n * 32) / 256, 256, 0, stream>>>(deg, x, dis, gbuf, n);
  k_scatter <<<(e + 255) / 256, 256, 0, stream>>>(srcv, dstv, cursor, csr_src, e);
  k_wsplit  <<<28, 256, 0, stream>>>(Ws, Wt, W1, W2, Wmu, W5, W6, Wth, Wtl);

  const unsigned short* wh[7]; const unsigned short* wl[7];
  for (int i = 0; i < 7; ++i){ wh[i] = Wth + (size_t)i * 16384; wl[i] = Wtl + (size_t)i * 16384; }

  // layer 0: agg once, then s/t/g1 off the same A tile
  k_agg<<<n / 4, 256, 0, stream>>>(gbuf, row_ptr, csr_src, Ahi, Alo, n);
  {
    GemmArgs a{};
    a.wh[0] = wh[0]; a.wl[0] = wl[0]; a.bias[0] = bs; a.out[0] = sb;   a.mode[0] = 4;      // s -> bf16
    a.wh[1] = wh[1]; a.wl[1] = wl[1]; a.bias[1] = bt; a.out[1] = tb;   a.mode[1] = 4;      // t -> bf16
    a.wh[2] = wh[2]; a.wl[2] = wl[2]; a.bias[2] = b1; a.out[2] = gbuf; a.mode[2] = 3;      // g1 = dis*relu(h1)
    a.nw = 3;
    k_gemm<<<n / 32, 256, 0, stream>>>(Ahi, Alo, dis, a);
  }

  // adj = s@t^T merged with layer-2 aggregation (independent, overlap)
  k_adjagg<<<NADJ + n / 4, 256, 0, stream>>>(sb, tb, adj, n, gbuf, row_ptr, csr_src, Ahi, Alo);

  auto gemm1 = [&](int wi, const float* bias, void* out, int mode){
    GemmArgs a{};
    a.wh[0] = wh[wi]; a.wl[0] = wl[wi]; a.bias[0] = bias; a.out[0] = out; a.mode[0] = mode;
    a.nw = 1;
    k_gemm<<<n / 32, 256, 0, stream>>>(Ahi, Alo, dis, a);
  };

  gemm1(3, b2, gbuf, 3);                                              // g2 = dis*relu(h2)
  k_agg<<<n / 4, 256, 0, stream>>>(gbuf, row_ptr, csr_src, Ahi, Alo, n);
  gemm1(4, bmu, gbuf, 2);                                             // gmu = dis*hmu (no relu)
  k_agg<<<n / 4, 256, 0, stream>>>(gbuf, row_ptr, csr_src, Ahi, Alo, n);
  gemm1(5, b5, gbuf, 3);                                              // g5 = dis*relu(h5)
  k_agg<<<n / 4, 256, 0, stream>>>(gbuf, row_ptr, csr_src, Ahi, Alo, n);
  gemm1(6, b6, hout, 1);                                              // h6 = relu(h6) -> output
}